// Round 16
// baseline (267.788 us; speedup 1.0000x reference)
//
#include <hip/hip_runtime.h>
#include <math.h>

namespace {

constexpr int kB  = 2;
constexpr int kS  = 2048;
constexpr int kD  = 512;
constexpr int kH  = 8;
constexpr int kDK = 64;
constexpr int kM  = kB * kS;   // 4096 rows
constexpr int kBH = kB * kH;   // 16

typedef __attribute__((ext_vector_type(8))) short bf16x8;
typedef __attribute__((ext_vector_type(4))) float f32x4;

__device__ __forceinline__ float wave_sum64(float v) {
#pragma unroll
    for (int o = 32; o > 0; o >>= 1) v += __shfl_xor(v, o, 64);
    return v;
}

__device__ __forceinline__ unsigned short f2bf(float f) {
    unsigned u = __float_as_uint(f);
    unsigned r = (u + 0x7FFF + ((u >> 16) & 1)) >> 16;   // round-to-nearest-even
    return (unsigned short)r;
}
__device__ __forceinline__ float bf2f(unsigned short h) {
    return __uint_as_float(((unsigned)h) << 16);
}

__device__ __forceinline__ bf16x8 mk_bf8(unsigned p0, unsigned p1) {
    union { unsigned u[4]; bf16x8 v; } t;
    t.u[0] = p0; t.u[1] = p1; t.u[2] = 0; t.u[3] = 0;   // hi half exact zeros (K pad)
    return t.v;
}
__device__ __forceinline__ bf16x8 mk_bf8_full(unsigned p0, unsigned p1,
                                              unsigned p2, unsigned p3) {
    union { unsigned u[4]; bf16x8 v; } t;
    t.u[0] = p0; t.u[1] = p1; t.u[2] = p2; t.u[3] = p3;
    return t.v;
}

#define MAXN_F  ((float)(1.0 - 1e-5))
#define ACLIP_F ((float)(1.0 - 1e-7))

// ---- core split-bf16 MFMA GEMM body: Y(Mx512) = X @ W^T, 64x64 tile ----
__device__ __forceinline__ void gemm_body(const float* __restrict__ X,
                                          const float* __restrict__ W,
                                          float* __restrict__ Y,
                                          int m0, int n0, int tid) {
    __shared__ unsigned short Ah[64 * 64], Al[64 * 64], Bh[64 * 64], Bl[64 * 64];
    const int w = tid >> 6, l = tid & 63;
    const int lr = l & 15, lh = l >> 4;
    const int sr = tid >> 2;          // staging row 0..63
    const int sk = (tid & 3) * 16;    // staging k base (16 elems/thread)
    float4 xr[4], wr[4];
#pragma unroll
    for (int i = 0; i < 4; ++i) {
        xr[i] = *(const float4*)(X + (size_t)(m0 + sr) * 512 + sk + i * 4);
        wr[i] = *(const float4*)(W + (size_t)(n0 + sr) * 512 + sk + i * 4);
    }
    f32x4 acc[4];
#pragma unroll
    for (int j = 0; j < 4; ++j) acc[j] = (f32x4){0.f, 0.f, 0.f, 0.f};

    for (int c = 0; c < 8; ++c) {
        if (c) __syncthreads();       // previous MFMA done reading LDS
        {
            unsigned hx[8], lx[8], hw_[8], lw_[8];
#pragma unroll
            for (int t = 0; t < 8; ++t) {
                float e0 = ((const float*)&xr[t >> 1])[(t & 1) * 2 + 0];
                float e1 = ((const float*)&xr[t >> 1])[(t & 1) * 2 + 1];
                unsigned short h0 = f2bf(e0), h1 = f2bf(e1);
                hx[t] = (unsigned)h0 | ((unsigned)h1 << 16);
                lx[t] = (unsigned)f2bf(e0 - bf2f(h0)) | ((unsigned)f2bf(e1 - bf2f(h1)) << 16);
                float f0 = ((const float*)&wr[t >> 1])[(t & 1) * 2 + 0];
                float f1 = ((const float*)&wr[t >> 1])[(t & 1) * 2 + 1];
                unsigned short g0 = f2bf(f0), g1 = f2bf(f1);
                hw_[t] = (unsigned)g0 | ((unsigned)g1 << 16);
                lw_[t] = (unsigned)f2bf(f0 - bf2f(g0)) | ((unsigned)f2bf(f1 - bf2f(g1)) << 16);
            }
            const int ga = (sk >> 3) ^ (sr & 7);
            const int gb = ((sk >> 3) + 1) ^ (sr & 7);
            *(uint4*)&Ah[sr * 64 + ga * 8] = make_uint4(hx[0], hx[1], hx[2], hx[3]);
            *(uint4*)&Ah[sr * 64 + gb * 8] = make_uint4(hx[4], hx[5], hx[6], hx[7]);
            *(uint4*)&Al[sr * 64 + ga * 8] = make_uint4(lx[0], lx[1], lx[2], lx[3]);
            *(uint4*)&Al[sr * 64 + gb * 8] = make_uint4(lx[4], lx[5], lx[6], lx[7]);
            *(uint4*)&Bh[sr * 64 + ga * 8] = make_uint4(hw_[0], hw_[1], hw_[2], hw_[3]);
            *(uint4*)&Bh[sr * 64 + gb * 8] = make_uint4(hw_[4], hw_[5], hw_[6], hw_[7]);
            *(uint4*)&Bl[sr * 64 + ga * 8] = make_uint4(lw_[0], lw_[1], lw_[2], lw_[3]);
            *(uint4*)&Bl[sr * 64 + gb * 8] = make_uint4(lw_[4], lw_[5], lw_[6], lw_[7]);
        }
        if (c < 7) {
            const int k1 = (c + 1) * 64;
#pragma unroll
            for (int i = 0; i < 4; ++i) {
                xr[i] = *(const float4*)(X + (size_t)(m0 + sr) * 512 + k1 + sk + i * 4);
                wr[i] = *(const float4*)(W + (size_t)(n0 + sr) * 512 + k1 + sk + i * 4);
            }
        }
        __syncthreads();
#pragma unroll
        for (int ks = 0; ks < 2; ++ks) {
            const int kb = ks * 4 + lh;
            const int row = w * 16 + lr;
            const int aoff = row * 64 + ((kb ^ (row & 7)) << 3);
            bf16x8 ah = *(const bf16x8*)&Ah[aoff];
            bf16x8 al = *(const bf16x8*)&Al[aoff];
#pragma unroll
            for (int fn = 0; fn < 4; ++fn) {
                const int col = fn * 16 + lr;
                const int boff = col * 64 + ((kb ^ (col & 7)) << 3);
                bf16x8 bh8 = *(const bf16x8*)&Bh[boff];
                bf16x8 bl8 = *(const bf16x8*)&Bl[boff];
                acc[fn] = __builtin_amdgcn_mfma_f32_16x16x32_bf16(ah, bh8, acc[fn], 0, 0, 0);
                acc[fn] = __builtin_amdgcn_mfma_f32_16x16x32_bf16(al, bh8, acc[fn], 0, 0, 0);
                acc[fn] = __builtin_amdgcn_mfma_f32_16x16x32_bf16(ah, bl8, acc[fn], 0, 0, 0);
            }
        }
    }
#pragma unroll
    for (int fn = 0; fn < 4; ++fn)
#pragma unroll
        for (int r = 0; r < 4; ++r)
            Y[(size_t)(m0 + w * 16 + lh * 4 + r) * 512 + n0 + fn * 16 + lr] = acc[fn][r];
}

__global__ __launch_bounds__(256) void gemm_mfma(const float* __restrict__ X,
                                                 const float* __restrict__ W,
                                                 float* __restrict__ Y) {
    gemm_body(X, W, Y, blockIdx.x * 64, blockIdx.y * 64, threadIdx.x);
}

// batched QKV projection: blockIdx.z selects {q,k,v} (uniform branch)
__global__ __launch_bounds__(256) void gemm_mfma3(const float* __restrict__ X0,
                                                  const float* __restrict__ X1,
                                                  const float* __restrict__ X2,
                                                  const float* __restrict__ W0,
                                                  const float* __restrict__ W1,
                                                  const float* __restrict__ W2,
                                                  float* __restrict__ Y0,
                                                  float* __restrict__ Y1,
                                                  float* __restrict__ Y2) {
    const float* X = (blockIdx.z == 0) ? X0 : (blockIdx.z == 1) ? X1 : X2;
    const float* W = (blockIdx.z == 0) ? W0 : (blockIdx.z == 1) ? W1 : W2;
    float*       Y = (blockIdx.z == 0) ? Y0 : (blockIdx.z == 1) ? Y1 : Y2;
    gemm_body(X, W, Y, blockIdx.x * 64, blockIdx.y * 64, threadIdx.x);
}

// --------- mobius_linear tail: res=matvec scale; mobius_add(res,b); project ---------
__device__ __forceinline__ void rowops_body(const float* __restrict__ X,
                                            const float* __restrict__ MX,
                                            const float* __restrict__ bvec,
                                            float* __restrict__ out, int row, int tid) {
    __shared__ float4 red4[4];
    __shared__ float red1[4];
    const float2 xv = ((const float2*)(X + (size_t)row * kD))[tid];
    const float2 mv = ((const float2*)(MX + (size_t)row * kD))[tid];
    const float2 bv = ((const float2*)bvec)[tid];
    float sx  = fmaf(xv.x, xv.x, xv.y * xv.y);
    float sm  = fmaf(mv.x, mv.x, mv.y * mv.y);
    float smb = fmaf(mv.x, bv.x, mv.y * bv.y);
    float sb  = fmaf(bv.x, bv.x, bv.y * bv.y);
#pragma unroll
    for (int o = 32; o > 0; o >>= 1) {
        sx  += __shfl_xor(sx, o, 64);
        sm  += __shfl_xor(sm, o, 64);
        smb += __shfl_xor(smb, o, 64);
        sb  += __shfl_xor(sb, o, 64);
    }
    if ((tid & 63) == 0) red4[tid >> 6] = make_float4(sx, sm, smb, sb);
    __syncthreads();
    {
        float4 r0 = red4[0], r1 = red4[1], r2 = red4[2], r3 = red4[3];
        sx  = r0.x + r1.x + r2.x + r3.x;
        sm  = r0.y + r1.y + r2.y + r3.y;
        smb = r0.z + r1.z + r2.z + r3.z;
        sb  = r0.w + r1.w + r2.w + r3.w;
    }
    float xn  = sqrtf(fmaxf(sx, 1e-15f));
    float mxn = sqrtf(fmaxf(sm, 1e-15f));
    float xc  = fminf(xn, ACLIP_F);
    float at  = 0.5f * logf((1.f + xc) / (1.f - xc));       // artanh(xn)
    float sc  = tanhf(mxn / xn * at) / mxn;                 // res = sc * mx
    if (sm == 0.f) sc = 0.f;                                // all(mx==0) branch
    float x2 = sc * sc * sm;
    float xy = sc * smb;
    float y2 = sb;
    float c1 = 1.f + 2.f * xy + y2;
    float c2 = 1.f - x2;
    float den = fmaxf(1.f + 2.f * xy + x2 * y2, 1e-15f);
    float idn = 1.f / den;
    float ux = (c1 * sc * mv.x + c2 * bv.x) * idn;
    float uy = (c1 * sc * mv.y + c2 * bv.y) * idn;
    float su = wave_sum64(fmaf(ux, ux, uy * uy));
    if ((tid & 63) == 0) red1[tid >> 6] = su;
    __syncthreads();
    su = (red1[0] + red1[1]) + (red1[2] + red1[3]);
    float n = sqrtf(fmaxf(su, 1e-15f));
    float f = (n > MAXN_F) ? (MAXN_F / n) : 1.f;
    ((float2*)(out + (size_t)row * kD))[tid] = make_float2(ux * f, uy * f);
}

__global__ __launch_bounds__(256) void rowops(const float* __restrict__ X,
                                              const float* __restrict__ MX,
                                              const float* __restrict__ bvec,
                                              float* __restrict__ out) {
    rowops_body(X, MX, bvec, out, blockIdx.x, threadIdx.x);
}

__global__ __launch_bounds__(256) void rowops3(const float* __restrict__ X0,
                                               const float* __restrict__ X1,
                                               const float* __restrict__ X2,
                                               const float* __restrict__ MX0,
                                               const float* __restrict__ MX1,
                                               const float* __restrict__ MX2,
                                               const float* __restrict__ b0,
                                               const float* __restrict__ b1,
                                               const float* __restrict__ b2,
                                               float* __restrict__ o0,
                                               float* __restrict__ o1,
                                               float* __restrict__ o2) {
    const int z = blockIdx.y;
    const float* X  = (z == 0) ? X0  : (z == 1) ? X1  : X2;
    const float* MX = (z == 0) ? MX0 : (z == 1) ? MX1 : MX2;
    const float* bv = (z == 0) ? b0  : (z == 1) ? b1  : b2;
    float*       o  = (z == 0) ? o0  : (z == 1) ? o1  : o2;
    rowops_body(X, MX, bv, o, blockIdx.x, threadIdx.x);
}

// ---- prep3 = prep2 + split_qk fused ----
__global__ __launch_bounds__(256) void prep3(const float* __restrict__ Qp,
                                             const float* __restrict__ Kp,
                                             const float* __restrict__ Vp,
                                             float* __restrict__ qn2,
                                             float* __restrict__ kn2,
                                             unsigned short* __restrict__ LVbT,
                                             unsigned short* __restrict__ Qhi,
                                             unsigned short* __restrict__ Qlo,
                                             unsigned short* __restrict__ Khi,
                                             unsigned short* __restrict__ Klo) {
    __shared__ unsigned short T[64][66];   // [n][s_local], 66 -> 2-way banks (free)
    const int bh = blockIdx.x >> 5;
    const int k0 = (blockIdx.x & 31) * 64;
    const int b = bh >> 3, h = bh & 7;
    const int w = threadIdx.x >> 6, l = threadIdx.x & 63;
#pragma unroll 4
    for (int i = 0; i < 16; ++i) {
        const int s = k0 + w * 16 + i;
        const size_t src = (size_t)(b * kS + s) * kD + h * kDK + l;
        const size_t gdst = (((size_t)(bh << 11) + s) << 6) + l;
        float qv = Qp[src], kv = Kp[src], vv = Vp[src];
        unsigned short qh = f2bf(qv);
        Qhi[gdst] = qh;
        Qlo[gdst] = f2bf(qv - bf2f(qh));
        unsigned short kh = f2bf(kv);
        Khi[gdst] = kh;
        Klo[gdst] = f2bf(kv - bf2f(kh));
        float sq = wave_sum64(qv * qv);
        float sk = wave_sum64(kv * kv);
        float sv = wave_sum64(vv * vv);
        if (l == 0) { qn2[(bh << 11) + s] = sq; kn2[(bh << 11) + s] = sk; }
        float yn = sqrtf(fmaxf(sv, 1e-15f));
        float yc = fminf(yn, ACLIP_F);
        float coef = 0.5f * logf((1.f + yc) / (1.f - yc)) / yn;
        T[l][w * 16 + i] = f2bf(vv * coef);
    }
    __syncthreads();
    const int n = threadIdx.x >> 2, kk = (threadIdx.x & 3) * 16;
    const unsigned int* Tr = (const unsigned int*)&T[n][kk];
    unsigned int u0 = Tr[0], u1 = Tr[1], u2 = Tr[2], u3 = Tr[3];
    unsigned int u4 = Tr[4], u5 = Tr[5], u6 = Tr[6], u7 = Tr[7];
    unsigned short* dst = LVbT + (((size_t)(bh * 64 + n)) << 11) + k0 + kk;
    *(uint4*)dst = make_uint4(u0, u1, u2, u3);
    *(uint4*)(dst + 8) = make_uint4(u4, u5, u6, u7);
}

// ================= fused_attn (swapped-QK, register-fed PV, tile-paired K=32) =========
__global__ __launch_bounds__(256) void fused_attn(const unsigned short* __restrict__ Qhi,
                                                  const unsigned short* __restrict__ Qlo,
                                                  const unsigned short* __restrict__ Khi,
                                                  const unsigned short* __restrict__ Klo,
                                                  const unsigned short* __restrict__ LVbT,
                                                  const float* __restrict__ qn2,
                                                  const float* __restrict__ kn2,
                                                  float* __restrict__ attn,
                                                  float* __restrict__ outcat) {
    __shared__ unsigned long long smem_raw[4096];   // 32 KB
    unsigned short* KshH = (unsigned short*)smem_raw;        // 8 KB  [j][d]
    unsigned short* KshL = KshH + 4096;                       // 8 KB
    unsigned short* LVsh = KshL + 4096;                       // 8 KB  [dk][j]
    unsigned short* Psh  = LVsh + 4096;                       // 4 KB  [q][j]
    float* Pmid = (float*)smem_raw;                           // 32 KB alias (post-loop)
    __shared__ float rsL[4][32];
    __shared__ float invSL[32];
    unsigned short* eattn = (unsigned short*)attn;

    const int wgid = blockIdx.x;
    const int x = wgid & 7, bq_ = wgid >> 3;
    const int bh = 2 * x + (bq_ >> 6);
    const int i0 = (bq_ & 63) * 32;
    const int b = bh >> 3, h = bh & 7;
    const int tid = threadIdx.x;
    const int w = tid >> 6, l = tid & 63;
    const int lr = l & 15, lh = l >> 4;
    const int srj = tid >> 2;
    const int skk = (tid & 3) * 16;
    const size_t kvbase = ((size_t)(bh << 11)) << 6;
    const size_t lvbase = ((size_t)bh) << 17;

    bf16x8 qah[2][2], qal[2][2];
#pragma unroll
    for (int fm = 0; fm < 2; ++fm)
#pragma unroll
        for (int ks = 0; ks < 2; ++ks) {
            const size_t a = ((size_t)(bh << 11) + i0 + fm * 16 + lr) * 64 + (ks * 4 + lh) * 8;
            qah[fm][ks] = *(const bf16x8*)&Qhi[a];
            qal[fm][ks] = *(const bf16x8*)&Qlo[a];
        }
    float x2s[2];
    x2s[0] = qn2[(bh << 11) + i0 + 0 * 16 + lr];
    x2s[1] = qn2[(bh << 11) + i0 + 1 * 16 + lr];

    const int ga = (((skk >> 3) ^ (srj & 7)) << 3);
    const int gb = ((((skk >> 3) + 1) ^ (srj & 7)) << 3);
    const int jrow = w * 16 + lr;
    const int aoff0 = jrow * 64;
    uint4 pA0, pA1, pB0, pB1, pC0, pC1;
    {
        const unsigned short* kh = Khi + kvbase + (size_t)srj * 64 + skk;
        const unsigned short* kl = Klo + kvbase + (size_t)srj * 64 + skk;
        const unsigned short* lv = LVbT + lvbase + (size_t)srj * 2048 + skk;
        pA0 = *(const uint4*)kh; pA1 = *(const uint4*)(kh + 8);
        pB0 = *(const uint4*)kl; pB1 = *(const uint4*)(kl + 8);
        pC0 = *(const uint4*)lv; pC1 = *(const uint4*)(lv + 8);
    }

    f32x4 pvacc[2][4];
#pragma unroll
    for (int fm = 0; fm < 2; ++fm)
#pragma unroll
        for (int g2 = 0; g2 < 4; ++g2) pvacc[fm][g2] = (f32x4){0.f, 0.f, 0.f, 0.f};
    float rsp[2] = {0.f, 0.f};

    const int fl_row = tid >> 3, fl_g = tid & 7;
    const int pgj = w * 2 + (lh >> 1);
    const int pjo = (lh & 1) * 4;

    unsigned ep0[2], ep1[2];   // even-tile e packs (per fm)
    uint2 lvs[4];              // even-tile LV fragments (per g2)

    for (int t = 0; t < 32; ++t) {
        const int j0 = t * 64;
        __syncthreads();
        if (t) {
            uint4 ev = *(const uint4*)&Psh[fl_row * 64 + ((fl_g ^ (fl_row & 7)) << 3)];
            *(uint4*)(eattn + ((size_t)(bh << 11) + i0 + fl_row) * 4096 +
                      (j0 - 64) + fl_g * 8) = ev;
        }
        *(uint4*)&KshH[srj * 64 + ga] = pA0; *(uint4*)&KshH[srj * 64 + gb] = pA1;
        *(uint4*)&KshL[srj * 64 + ga] = pB0; *(uint4*)&KshL[srj * 64 + gb] = pB1;
        *(uint4*)&LVsh[srj * 64 + ga] = pC0; *(uint4*)&LVsh[srj * 64 + gb] = pC1;
        if (t < 31) {
            const unsigned short* kh = Khi + kvbase + (size_t)(j0 + 64 + srj) * 64 + skk;
            const unsigned short* kl = Klo + kvbase + (size_t)(j0 + 64 + srj) * 64 + skk;
            const unsigned short* lv = LVbT + lvbase + (size_t)srj * 2048 + j0 + 64 + skk;
            pA0 = *(const uint4*)kh; pA1 = *(const uint4*)(kh + 8);
            pB0 = *(const uint4*)kl; pB1 = *(const uint4*)(kl + 8);
            pC0 = *(const uint4*)lv; pC1 = *(const uint4*)(lv + 8);
        }
        __syncthreads();
        f32x4 sacc[2];
        sacc[0] = (f32x4){0.f, 0.f, 0.f, 0.f};
        sacc[1] = (f32x4){0.f, 0.f, 0.f, 0.f};
#pragma unroll
        for (int ks = 0; ks < 2; ++ks) {
            const int kb = ks * 4 + lh;
            const int aoff = aoff0 + ((kb ^ (jrow & 7)) << 3);
            bf16x8 kh8 = *(const bf16x8*)&KshH[aoff];
            bf16x8 kl8 = *(const bf16x8*)&KshL[aoff];
#pragma unroll
            for (int fm = 0; fm < 2; ++fm) {
                sacc[fm] = __builtin_amdgcn_mfma_f32_16x16x32_bf16(kh8, qah[fm][ks], sacc[fm], 0, 0, 0);
                sacc[fm] = __builtin_amdgcn_mfma_f32_16x16x32_bf16(kh8, qal[fm][ks], sacc[fm], 0, 0, 0);
                sacc[fm] = __builtin_amdgcn_mfma_f32_16x16x32_bf16(kl8, qah[fm][ks], sacc[fm], 0, 0, 0);
            }
        }
        float4 y2v = *(const float4*)(kn2 + (bh << 11) + j0 + w * 16 + lh * 4);
        unsigned pp0[2], pp1[2];
#pragma unroll
        for (int fm = 0; fm < 2; ++fm) {
            const float x2 = x2s[fm];
            float es[4];
#pragma unroll
            for (int r = 0; r < 4; ++r) {
                float xy = sacc[fm][r];
                float y2 = ((const float*)&y2v)[r];
                float A_ = 1.f - 2.f * xy + y2;
                float Bc = 1.f - x2;
                float num2 = A_ * A_ * x2 + Bc * Bc * y2 - 2.f * A_ * Bc * xy;
                float den  = fmaxf(1.f - 2.f * xy + x2 * y2, 1e-15f);
                float sn   = __builtin_amdgcn_sqrtf(fmaxf(num2, 0.f));
                float dm   = den - sn;
                dm = fmaxf(dm, (den + sn) * 5e-8f);
                float rr = (den + sn) * __builtin_amdgcn_rcpf(dm);
                float e = __builtin_amdgcn_exp2f(-0.125f * __builtin_amdgcn_logf(rr));
                es[r] = e;
                rsp[fm] += e;
            }
            pp0[fm] = (unsigned)f2bf(es[0]) | ((unsigned)f2bf(es[1]) << 16);
            pp1[fm] = (unsigned)f2bf(es[2]) | ((unsigned)f2bf(es[3]) << 16);
            const int prow = fm * 16 + lr;
            *(uint2*)&Psh[prow * 64 + ((pgj ^ (prow & 7)) << 3) + pjo] =
                make_uint2(pp0[fm], pp1[fm]);
        }
        if ((t & 1) == 0) {
            // even tile: stash e-packs + LV fragments; PV deferred to the odd tile
            ep0[0] = pp0[0]; ep1[0] = pp1[0];
            ep0[1] = pp0[1]; ep1[1] = pp1[1];
#pragma unroll
            for (int g2 = 0; g2 < 4; ++g2) {
                const int dk = g2 * 16 + lr;
                lvs[g2] = *(const uint2*)&LVsh[dk * 64 + ((pgj ^ (dk & 7)) << 3) + pjo];
            }
        } else {
            // odd tile: full-K=32 PV for the pair (even j's in slots 0-1, odd in 2-3)
            bf16x8 ea0 = mk_bf8_full(ep0[0], ep1[0], pp0[0], pp1[0]);
            bf16x8 ea1 = mk_bf8_full(ep0[1], ep1[1], pp0[1], pp1[1]);
#pragma unroll
            for (int g2 = 0; g2 < 4; ++g2) {
                const int dk = g2 * 16 + lr;
                uint2 lvp = *(const uint2*)&LVsh[dk * 64 + ((pgj ^ (dk & 7)) << 3) + pjo];
                bf16x8 bfr = mk_bf8_full(lvs[g2].x, lvs[g2].y, lvp.x, lvp.y);
                pvacc[0][g2] = __builtin_amdgcn_mfma_f32_16x16x32_bf16(ea0, bfr, pvacc[0][g2], 0, 0, 0);
                pvacc[1][g2] = __builtin_amdgcn_mfma_f32_16x16x32_bf16(ea1, bfr, pvacc[1][g2], 0, 0, 0);
            }
        }
    }
    __syncthreads();
    {
        uint4 ev = *(const uint4*)&Psh[fl_row * 64 + ((fl_g ^ (fl_row & 7)) << 3)];
        *(uint4*)(eattn + ((size_t)(bh << 11) + i0 + fl_row) * 4096 + 31 * 64 + fl_g * 8) = ev;
    }
#pragma unroll
    for (int fm = 0; fm < 2; ++fm) {
        rsp[fm] += __shfl_xor(rsp[fm], 16, 64);
        rsp[fm] += __shfl_xor(rsp[fm], 32, 64);
    }
    __syncthreads();
    if (l < 16) { rsL[w][l] = rsp[0]; rsL[w][16 + l] = rsp[1]; }
#pragma unroll
    for (int fm = 0; fm < 2; ++fm)
#pragma unroll
        for (int g2 = 0; g2 < 4; ++g2)
#pragma unroll
            for (int r = 0; r < 4; ++r)
                Pmid[w * 2048 + (fm * 16 + lh * 4 + r) * 64 + g2 * 16 + lr] = pvacc[fm][g2][r];
    __syncthreads();
    if (tid < 32)
        invSL[tid] = 1.f / (rsL[0][tid] + rsL[1][tid] + rsL[2][tid] + rsL[3][tid]);
    __syncthreads();
    {
        const int q = tid >> 3;
        const int c8 = (tid & 7) * 8;
        float m[8];
#pragma unroll
        for (int i = 0; i < 8; i += 4) {
            float4 a0 = *(const float4*)&Pmid[0 * 2048 + q * 64 + c8 + i];
            float4 a1 = *(const float4*)&Pmid[1 * 2048 + q * 64 + c8 + i];
            float4 a2 = *(const float4*)&Pmid[2 * 2048 + q * 64 + c8 + i];
            float4 a3 = *(const float4*)&Pmid[3 * 2048 + q * 64 + c8 + i];
            m[i + 0] = (a0.x + a1.x) + (a2.x + a3.x);
            m[i + 1] = (a0.y + a1.y) + (a2.y + a3.y);
            m[i + 2] = (a0.z + a1.z) + (a2.z + a3.z);
            m[i + 3] = (a0.w + a1.w) + (a2.w + a3.w);
        }
        const float is = invSL[q];
        float ns = 0.f;
#pragma unroll
        for (int i = 0; i < 8; ++i) { m[i] *= is; ns = fmaf(m[i], m[i], ns); }
        ns += __shfl_xor(ns, 1, 64);
        ns += __shfl_xor(ns, 2, 64);
        ns += __shfl_xor(ns, 4, 64);
        float un = sqrtf(fmaxf(ns, 1e-15f));
        float coef = tanhf(un) / un;
        float* dst = outcat + (size_t)(b * kS + i0 + q) * kD + h * kDK + c8;
        *(float4*)dst       = make_float4(m[0] * coef, m[1] * coef, m[2] * coef, m[3] * coef);
        *(float4*)(dst + 4) = make_float4(m[4] * coef, m[5] * coef, m[6] * coef, m[7] * coef);
    }
    // ---- tail: in-place expansion, 4 rows per barrier (8 barriers, 4x MLP) ----
    for (int r = 0; r < 32; r += 4) {
        uint4 ev[4];
        float is[4];
#pragma unroll
        for (int q = 0; q < 4; ++q) {
            ev[q] = *(const uint4*)(eattn + ((size_t)(bh << 11) + i0 + r + q) * 4096 + tid * 8);
            is[q] = invSL[r + q];
        }
        __syncthreads();          // all reads of the 4 rows complete before overwrite
#pragma unroll
        for (int q = 0; q < 4; ++q) {
            float o[8];
            o[0] = __uint_as_float(ev[q].x << 16) * is[q];
            o[1] = __uint_as_float(ev[q].x & 0xFFFF0000u) * is[q];
            o[2] = __uint_as_float(ev[q].y << 16) * is[q];
            o[3] = __uint_as_float(ev[q].y & 0xFFFF0000u) * is[q];
            o[4] = __uint_as_float(ev[q].z << 16) * is[q];
            o[5] = __uint_as_float(ev[q].z & 0xFFFF0000u) * is[q];
            o[6] = __uint_as_float(ev[q].w << 16) * is[q];
            o[7] = __uint_as_float(ev[q].w & 0xFFFF0000u) * is[q];
            float* d = attn + ((size_t)(bh << 11) + i0 + r + q) * kS + tid * 8;
            *(float4*)d       = make_float4(o[0], o[1], o[2], o[3]);
            *(float4*)(d + 4) = make_float4(o[4], o[5], o[6], o[7]);
        }
    }
}

} // namespace

extern "C" void kernel_launch(void* const* d_in, const int* in_sizes, int n_in,
                              void* d_out, int out_size, void* d_ws, size_t ws_size,
                              hipStream_t stream) {
    const float* q  = (const float*)d_in[0];
    const float* k  = (const float*)d_in[1];
    const float* v  = (const float*)d_in[2];
    const float* Wq = (const float*)d_in[3];
    const float* bq = (const float*)d_in[4];
    const float* Wk = (const float*)d_in[5];
    const float* bk = (const float*)d_in[6];
    const float* Wv = (const float*)d_in[7];
    const float* bv = (const float*)d_in[8];
    const float* Wo = (const float*)d_in[9];
    const float* bo = (const float*)d_in[10];

    float* out  = (float*)d_out;
    float* attn = out + (size_t)kM * kD;   // out (2M floats), then attn (64M floats)

    constexpr size_t NBUF = (size_t)kM * kD; // 2,097,152 floats (8 MB)
    float* ws  = (float*)d_ws;
    float* A0  = ws;              // Qp
    float* A1  = ws + NBUF;       // Kp -> later outcat
    float* A2  = ws + 2 * NBUF;   // Qhi/Qlo bf16 -> mx for final gemm
    float* A3  = ws + 3 * NBUF;   // mxq -> later LVbT (4MB)
    float* qn2 = ws + 4 * NBUF;                       // 32768 floats
    float* kn2 = qn2 + (size_t)kBH * kS;              // 32768 floats

    // projection scratch in the (later fully overwritten) attn region:
    float* mxq  = A3;
    float* mxk  = attn;                // attn rows 0..1023
    float* mxv  = attn + NBUF;         // attn rows 1024..2047
    float* VpBuf = attn + 2 * NBUF;    // attn rows 2048..3071

    constexpr size_t HP = (size_t)kBH * kS * kDK;   // 2,097,152 ushorts = 4 MB per plane
    unsigned short* Qhi = (unsigned short*)A2;
    unsigned short* Qlo = Qhi + HP;
    unsigned short* Khi = (unsigned short*)out;     // out region free until final rowops
    unsigned short* Klo = Khi + HP;
    unsigned short* LVbT = (unsigned short*)A3;     // overwrites mxq (dead after rowops3)

    dim3 gg(kM / 64, kD / 64);
    dim3 gg3(kM / 64, kD / 64, 3);
    dim3 rr3(kM, 3);

    gemm_mfma3<<<gg3, 256, 0, stream>>>(q, k, v, Wq, Wk, Wv, mxq, mxk, mxv);
    rowops3<<<rr3, 256, 0, stream>>>(q, k, v, mxq, mxk, mxv, bq, bk, bv, A0, A1, VpBuf);

    prep3<<<kBH * 32, 256, 0, stream>>>(A0, A1, VpBuf, qn2, kn2, LVbT,
                                        Qhi, Qlo, Khi, Klo);

    fused_attn<<<kBH * (kS / 32), 256, 0, stream>>>(Qhi, Qlo, Khi, Klo, LVbT,
                                                    qn2, kn2, attn, A1);

    gemm_mfma<<<gg, 256, 0, stream>>>(A1, Wo, A2);
    rowops<<<kM, 256, 0, stream>>>(A1, A2, bo, out);
}

// Round 17
// 255.604 us; speedup vs baseline: 1.0477x; 1.0477x over previous
//
#include <hip/hip_runtime.h>
#include <math.h>

namespace {

constexpr int kB  = 2;
constexpr int kS  = 2048;
constexpr int kD  = 512;
constexpr int kH  = 8;
constexpr int kDK = 64;
constexpr int kM  = kB * kS;   // 4096 rows
constexpr int kBH = kB * kH;   // 16

typedef __attribute__((ext_vector_type(8))) short bf16x8;
typedef __attribute__((ext_vector_type(4))) float f32x4;

__device__ __forceinline__ float wave_sum64(float v) {
#pragma unroll
    for (int o = 32; o > 0; o >>= 1) v += __shfl_xor(v, o, 64);
    return v;
}

__device__ __forceinline__ unsigned short f2bf(float f) {
    unsigned u = __float_as_uint(f);
    unsigned r = (u + 0x7FFF + ((u >> 16) & 1)) >> 16;   // round-to-nearest-even
    return (unsigned short)r;
}
__device__ __forceinline__ float bf2f(unsigned short h) {
    return __uint_as_float(((unsigned)h) << 16);
}

__device__ __forceinline__ bf16x8 mk_bf8(unsigned p0, unsigned p1) {
    union { unsigned u[4]; bf16x8 v; } t;
    t.u[0] = p0; t.u[1] = p1; t.u[2] = 0; t.u[3] = 0;   // hi half exact zeros (K pad)
    return t.v;
}

#define MAXN_F  ((float)(1.0 - 1e-5))
#define ACLIP_F ((float)(1.0 - 1e-7))

// ---- core split-bf16 MFMA GEMM body: Y(Mx512) = X @ W^T, 64x64 tile ----
__device__ __forceinline__ void gemm_body(const float* __restrict__ X,
                                          const float* __restrict__ W,
                                          float* __restrict__ Y,
                                          int m0, int n0, int tid) {
    __shared__ unsigned short Ah[64 * 64], Al[64 * 64], Bh[64 * 64], Bl[64 * 64];
    const int w = tid >> 6, l = tid & 63;
    const int lr = l & 15, lh = l >> 4;
    const int sr = tid >> 2;          // staging row 0..63
    const int sk = (tid & 3) * 16;    // staging k base (16 elems/thread)
    float4 xr[4], wr[4];
#pragma unroll
    for (int i = 0; i < 4; ++i) {
        xr[i] = *(const float4*)(X + (size_t)(m0 + sr) * 512 + sk + i * 4);
        wr[i] = *(const float4*)(W + (size_t)(n0 + sr) * 512 + sk + i * 4);
    }
    f32x4 acc[4];
#pragma unroll
    for (int j = 0; j < 4; ++j) acc[j] = (f32x4){0.f, 0.f, 0.f, 0.f};

    for (int c = 0; c < 8; ++c) {
        if (c) __syncthreads();       // previous MFMA done reading LDS
        {
            unsigned hx[8], lx[8], hw_[8], lw_[8];
#pragma unroll
            for (int t = 0; t < 8; ++t) {
                float e0 = ((const float*)&xr[t >> 1])[(t & 1) * 2 + 0];
                float e1 = ((const float*)&xr[t >> 1])[(t & 1) * 2 + 1];
                unsigned short h0 = f2bf(e0), h1 = f2bf(e1);
                hx[t] = (unsigned)h0 | ((unsigned)h1 << 16);
                lx[t] = (unsigned)f2bf(e0 - bf2f(h0)) | ((unsigned)f2bf(e1 - bf2f(h1)) << 16);
                float f0 = ((const float*)&wr[t >> 1])[(t & 1) * 2 + 0];
                float f1 = ((const float*)&wr[t >> 1])[(t & 1) * 2 + 1];
                unsigned short g0 = f2bf(f0), g1 = f2bf(f1);
                hw_[t] = (unsigned)g0 | ((unsigned)g1 << 16);
                lw_[t] = (unsigned)f2bf(f0 - bf2f(g0)) | ((unsigned)f2bf(f1 - bf2f(g1)) << 16);
            }
            const int ga = (sk >> 3) ^ (sr & 7);
            const int gb = ((sk >> 3) + 1) ^ (sr & 7);
            *(uint4*)&Ah[sr * 64 + ga * 8] = make_uint4(hx[0], hx[1], hx[2], hx[3]);
            *(uint4*)&Ah[sr * 64 + gb * 8] = make_uint4(hx[4], hx[5], hx[6], hx[7]);
            *(uint4*)&Al[sr * 64 + ga * 8] = make_uint4(lx[0], lx[1], lx[2], lx[3]);
            *(uint4*)&Al[sr * 64 + gb * 8] = make_uint4(lx[4], lx[5], lx[6], lx[7]);
            *(uint4*)&Bh[sr * 64 + ga * 8] = make_uint4(hw_[0], hw_[1], hw_[2], hw_[3]);
            *(uint4*)&Bh[sr * 64 + gb * 8] = make_uint4(hw_[4], hw_[5], hw_[6], hw_[7]);
            *(uint4*)&Bl[sr * 64 + ga * 8] = make_uint4(lw_[0], lw_[1], lw_[2], lw_[3]);
            *(uint4*)&Bl[sr * 64 + gb * 8] = make_uint4(lw_[4], lw_[5], lw_[6], lw_[7]);
        }
        if (c < 7) {
            const int k1 = (c + 1) * 64;
#pragma unroll
            for (int i = 0; i < 4; ++i) {
                xr[i] = *(const float4*)(X + (size_t)(m0 + sr) * 512 + k1 + sk + i * 4);
                wr[i] = *(const float4*)(W + (size_t)(n0 + sr) * 512 + k1 + sk + i * 4);
            }
        }
        __syncthreads();
#pragma unroll
        for (int ks = 0; ks < 2; ++ks) {
            const int kb = ks * 4 + lh;
            const int row = w * 16 + lr;
            const int aoff = row * 64 + ((kb ^ (row & 7)) << 3);
            bf16x8 ah = *(const bf16x8*)&Ah[aoff];
            bf16x8 al = *(const bf16x8*)&Al[aoff];
#pragma unroll
            for (int fn = 0; fn < 4; ++fn) {
                const int col = fn * 16 + lr;
                const int boff = col * 64 + ((kb ^ (col & 7)) << 3);
                bf16x8 bh8 = *(const bf16x8*)&Bh[boff];
                bf16x8 bl8 = *(const bf16x8*)&Bl[boff];
                acc[fn] = __builtin_amdgcn_mfma_f32_16x16x32_bf16(ah, bh8, acc[fn], 0, 0, 0);
                acc[fn] = __builtin_amdgcn_mfma_f32_16x16x32_bf16(al, bh8, acc[fn], 0, 0, 0);
                acc[fn] = __builtin_amdgcn_mfma_f32_16x16x32_bf16(ah, bl8, acc[fn], 0, 0, 0);
            }
        }
    }
#pragma unroll
    for (int fn = 0; fn < 4; ++fn)
#pragma unroll
        for (int r = 0; r < 4; ++r)
            Y[(size_t)(m0 + w * 16 + lh * 4 + r) * 512 + n0 + fn * 16 + lr] = acc[fn][r];
}

__global__ __launch_bounds__(256) void gemm_mfma(const float* __restrict__ X,
                                                 const float* __restrict__ W,
                                                 float* __restrict__ Y) {
    gemm_body(X, W, Y, blockIdx.x * 64, blockIdx.y * 64, threadIdx.x);
}

// batched QKV projection: blockIdx.z selects {q,k,v} (uniform branch)
__global__ __launch_bounds__(256) void gemm_mfma3(const float* __restrict__ X0,
                                                  const float* __restrict__ X1,
                                                  const float* __restrict__ X2,
                                                  const float* __restrict__ W0,
                                                  const float* __restrict__ W1,
                                                  const float* __restrict__ W2,
                                                  float* __restrict__ Y0,
                                                  float* __restrict__ Y1,
                                                  float* __restrict__ Y2) {
    const float* X = (blockIdx.z == 0) ? X0 : (blockIdx.z == 1) ? X1 : X2;
    const float* W = (blockIdx.z == 0) ? W0 : (blockIdx.z == 1) ? W1 : W2;
    float*       Y = (blockIdx.z == 0) ? Y0 : (blockIdx.z == 1) ? Y1 : Y2;
    gemm_body(X, W, Y, blockIdx.x * 64, blockIdx.y * 64, threadIdx.x);
}

// --------- mobius_linear tail: res=matvec scale; mobius_add(res,b); project ---------
__device__ __forceinline__ void rowops_body(const float* __restrict__ X,
                                            const float* __restrict__ MX,
                                            const float* __restrict__ bvec,
                                            float* __restrict__ out, int row, int tid) {
    __shared__ float4 red4[4];
    __shared__ float red1[4];
    const float2 xv = ((const float2*)(X + (size_t)row * kD))[tid];
    const float2 mv = ((const float2*)(MX + (size_t)row * kD))[tid];
    const float2 bv = ((const float2*)bvec)[tid];
    float sx  = fmaf(xv.x, xv.x, xv.y * xv.y);
    float sm  = fmaf(mv.x, mv.x, mv.y * mv.y);
    float smb = fmaf(mv.x, bv.x, mv.y * bv.y);
    float sb  = fmaf(bv.x, bv.x, bv.y * bv.y);
#pragma unroll
    for (int o = 32; o > 0; o >>= 1) {
        sx  += __shfl_xor(sx, o, 64);
        sm  += __shfl_xor(sm, o, 64);
        smb += __shfl_xor(smb, o, 64);
        sb  += __shfl_xor(sb, o, 64);
    }
    if ((tid & 63) == 0) red4[tid >> 6] = make_float4(sx, sm, smb, sb);
    __syncthreads();
    {
        float4 r0 = red4[0], r1 = red4[1], r2 = red4[2], r3 = red4[3];
        sx  = r0.x + r1.x + r2.x + r3.x;
        sm  = r0.y + r1.y + r2.y + r3.y;
        smb = r0.z + r1.z + r2.z + r3.z;
        sb  = r0.w + r1.w + r2.w + r3.w;
    }
    float xn  = sqrtf(fmaxf(sx, 1e-15f));
    float mxn = sqrtf(fmaxf(sm, 1e-15f));
    float xc  = fminf(xn, ACLIP_F);
    float at  = 0.5f * logf((1.f + xc) / (1.f - xc));       // artanh(xn)
    float sc  = tanhf(mxn / xn * at) / mxn;                 // res = sc * mx
    if (sm == 0.f) sc = 0.f;                                // all(mx==0) branch
    float x2 = sc * sc * sm;
    float xy = sc * smb;
    float y2 = sb;
    float c1 = 1.f + 2.f * xy + y2;
    float c2 = 1.f - x2;
    float den = fmaxf(1.f + 2.f * xy + x2 * y2, 1e-15f);
    float idn = 1.f / den;
    float ux = (c1 * sc * mv.x + c2 * bv.x) * idn;
    float uy = (c1 * sc * mv.y + c2 * bv.y) * idn;
    float su = wave_sum64(fmaf(ux, ux, uy * uy));
    if ((tid & 63) == 0) red1[tid >> 6] = su;
    __syncthreads();
    su = (red1[0] + red1[1]) + (red1[2] + red1[3]);
    float n = sqrtf(fmaxf(su, 1e-15f));
    float f = (n > MAXN_F) ? (MAXN_F / n) : 1.f;
    ((float2*)(out + (size_t)row * kD))[tid] = make_float2(ux * f, uy * f);
}

__global__ __launch_bounds__(256) void rowops(const float* __restrict__ X,
                                              const float* __restrict__ MX,
                                              const float* __restrict__ bvec,
                                              float* __restrict__ out) {
    rowops_body(X, MX, bvec, out, blockIdx.x, threadIdx.x);
}

__global__ __launch_bounds__(256) void rowops3(const float* __restrict__ X0,
                                               const float* __restrict__ X1,
                                               const float* __restrict__ X2,
                                               const float* __restrict__ MX0,
                                               const float* __restrict__ MX1,
                                               const float* __restrict__ MX2,
                                               const float* __restrict__ b0,
                                               const float* __restrict__ b1,
                                               const float* __restrict__ b2,
                                               float* __restrict__ o0,
                                               float* __restrict__ o1,
                                               float* __restrict__ o2) {
    const int z = blockIdx.y;
    const float* X  = (z == 0) ? X0  : (z == 1) ? X1  : X2;
    const float* MX = (z == 0) ? MX0 : (z == 1) ? MX1 : MX2;
    const float* bv = (z == 0) ? b0  : (z == 1) ? b1  : b2;
    float*       o  = (z == 0) ? o0  : (z == 1) ? o1  : o2;
    rowops_body(X, MX, bv, o, blockIdx.x, threadIdx.x);
}

// ---- prep3 = prep2 + split_qk fused ----
__global__ __launch_bounds__(256) void prep3(const float* __restrict__ Qp,
                                             const float* __restrict__ Kp,
                                             const float* __restrict__ Vp,
                                             float* __restrict__ qn2,
                                             float* __restrict__ kn2,
                                             unsigned short* __restrict__ LVbT,
                                             unsigned short* __restrict__ Qhi,
                                             unsigned short* __restrict__ Qlo,
                                             unsigned short* __restrict__ Khi,
                                             unsigned short* __restrict__ Klo) {
    __shared__ unsigned short T[64][66];   // [n][s_local], 66 -> 2-way banks (free)
    const int bh = blockIdx.x >> 5;
    const int k0 = (blockIdx.x & 31) * 64;
    const int b = bh >> 3, h = bh & 7;
    const int w = threadIdx.x >> 6, l = threadIdx.x & 63;
#pragma unroll 4
    for (int i = 0; i < 16; ++i) {
        const int s = k0 + w * 16 + i;
        const size_t src = (size_t)(b * kS + s) * kD + h * kDK + l;
        const size_t gdst = (((size_t)(bh << 11) + s) << 6) + l;
        float qv = Qp[src], kv = Kp[src], vv = Vp[src];
        unsigned short qh = f2bf(qv);
        Qhi[gdst] = qh;
        Qlo[gdst] = f2bf(qv - bf2f(qh));
        unsigned short kh = f2bf(kv);
        Khi[gdst] = kh;
        Klo[gdst] = f2bf(kv - bf2f(kh));
        float sq = wave_sum64(qv * qv);
        float sk = wave_sum64(kv * kv);
        float sv = wave_sum64(vv * vv);
        if (l == 0) { qn2[(bh << 11) + s] = sq; kn2[(bh << 11) + s] = sk; }
        float yn = sqrtf(fmaxf(sv, 1e-15f));
        float yc = fminf(yn, ACLIP_F);
        float coef = 0.5f * logf((1.f + yc) / (1.f - yc)) / yn;
        T[l][w * 16 + i] = f2bf(vv * coef);
    }
    __syncthreads();
    const int n = threadIdx.x >> 2, kk = (threadIdx.x & 3) * 16;
    const unsigned int* Tr = (const unsigned int*)&T[n][kk];
    unsigned int u0 = Tr[0], u1 = Tr[1], u2 = Tr[2], u3 = Tr[3];
    unsigned int u4 = Tr[4], u5 = Tr[5], u6 = Tr[6], u7 = Tr[7];
    unsigned short* dst = LVbT + (((size_t)(bh * 64 + n)) << 11) + k0 + kk;
    *(uint4*)dst = make_uint4(u0, u1, u2, u3);
    *(uint4*)(dst + 8) = make_uint4(u4, u5, u6, u7);
}

// ================= fused_attn (swapped-QK, register-fed PV) — round-15 config =========
__global__ __launch_bounds__(256) void fused_attn(const unsigned short* __restrict__ Qhi,
                                                  const unsigned short* __restrict__ Qlo,
                                                  const unsigned short* __restrict__ Khi,
                                                  const unsigned short* __restrict__ Klo,
                                                  const unsigned short* __restrict__ LVbT,
                                                  const float* __restrict__ qn2,
                                                  const float* __restrict__ kn2,
                                                  float* __restrict__ attn,
                                                  float* __restrict__ outcat) {
    __shared__ unsigned long long smem_raw[4096];   // 32 KB
    unsigned short* KshH = (unsigned short*)smem_raw;        // 8 KB  [j][d]
    unsigned short* KshL = KshH + 4096;                       // 8 KB
    unsigned short* LVsh = KshL + 4096;                       // 8 KB  [dk][j]
    unsigned short* Psh  = LVsh + 4096;                       // 4 KB  [q][j]
    float* Pmid = (float*)smem_raw;                           // 32 KB alias (post-loop)
    __shared__ float rsL[4][32];
    __shared__ float invSL[32];
    unsigned short* eattn = (unsigned short*)attn;

    const int wgid = blockIdx.x;
    const int x = wgid & 7, bq_ = wgid >> 3;
    const int bh = 2 * x + (bq_ >> 6);
    const int i0 = (bq_ & 63) * 32;
    const int b = bh >> 3, h = bh & 7;
    const int tid = threadIdx.x;
    const int w = tid >> 6, l = tid & 63;
    const int lr = l & 15, lh = l >> 4;
    const int srj = tid >> 2;
    const int skk = (tid & 3) * 16;
    const size_t kvbase = ((size_t)(bh << 11)) << 6;
    const size_t lvbase = ((size_t)bh) << 17;

    bf16x8 qah[2][2], qal[2][2];
#pragma unroll
    for (int fm = 0; fm < 2; ++fm)
#pragma unroll
        for (int ks = 0; ks < 2; ++ks) {
            const size_t a = ((size_t)(bh << 11) + i0 + fm * 16 + lr) * 64 + (ks * 4 + lh) * 8;
            qah[fm][ks] = *(const bf16x8*)&Qhi[a];
            qal[fm][ks] = *(const bf16x8*)&Qlo[a];
        }
    float x2s[2];
    x2s[0] = qn2[(bh << 11) + i0 + 0 * 16 + lr];
    x2s[1] = qn2[(bh << 11) + i0 + 1 * 16 + lr];

    const int ga = (((skk >> 3) ^ (srj & 7)) << 3);
    const int gb = ((((skk >> 3) + 1) ^ (srj & 7)) << 3);
    const int jrow = w * 16 + lr;
    const int aoff0 = jrow * 64;
    uint4 pA0, pA1, pB0, pB1, pC0, pC1;
    {
        const unsigned short* kh = Khi + kvbase + (size_t)srj * 64 + skk;
        const unsigned short* kl = Klo + kvbase + (size_t)srj * 64 + skk;
        const unsigned short* lv = LVbT + lvbase + (size_t)srj * 2048 + skk;
        pA0 = *(const uint4*)kh; pA1 = *(const uint4*)(kh + 8);
        pB0 = *(const uint4*)kl; pB1 = *(const uint4*)(kl + 8);
        pC0 = *(const uint4*)lv; pC1 = *(const uint4*)(lv + 8);
    }

    f32x4 pvacc[2][4];
#pragma unroll
    for (int fm = 0; fm < 2; ++fm)
#pragma unroll
        for (int g2 = 0; g2 < 4; ++g2) pvacc[fm][g2] = (f32x4){0.f, 0.f, 0.f, 0.f};
    float rsp[2] = {0.f, 0.f};

    const int fl_row = tid >> 3, fl_g = tid & 7;
    const int pgj = w * 2 + (lh >> 1);
    const int pjo = (lh & 1) * 4;

    for (int t = 0; t < 32; ++t) {
        const int j0 = t * 64;
        __syncthreads();
        if (t) {
            uint4 ev = *(const uint4*)&Psh[fl_row * 64 + ((fl_g ^ (fl_row & 7)) << 3)];
            *(uint4*)(eattn + ((size_t)(bh << 11) + i0 + fl_row) * 4096 +
                      (j0 - 64) + fl_g * 8) = ev;
        }
        *(uint4*)&KshH[srj * 64 + ga] = pA0; *(uint4*)&KshH[srj * 64 + gb] = pA1;
        *(uint4*)&KshL[srj * 64 + ga] = pB0; *(uint4*)&KshL[srj * 64 + gb] = pB1;
        *(uint4*)&LVsh[srj * 64 + ga] = pC0; *(uint4*)&LVsh[srj * 64 + gb] = pC1;
        if (t < 31) {
            const unsigned short* kh = Khi + kvbase + (size_t)(j0 + 64 + srj) * 64 + skk;
            const unsigned short* kl = Klo + kvbase + (size_t)(j0 + 64 + srj) * 64 + skk;
            const unsigned short* lv = LVbT + lvbase + (size_t)srj * 2048 + j0 + 64 + skk;
            pA0 = *(const uint4*)kh; pA1 = *(const uint4*)(kh + 8);
            pB0 = *(const uint4*)kl; pB1 = *(const uint4*)(kl + 8);
            pC0 = *(const uint4*)lv; pC1 = *(const uint4*)(lv + 8);
        }
        __syncthreads();
        f32x4 sacc[2];
        sacc[0] = (f32x4){0.f, 0.f, 0.f, 0.f};
        sacc[1] = (f32x4){0.f, 0.f, 0.f, 0.f};
#pragma unroll
        for (int ks = 0; ks < 2; ++ks) {
            const int kb = ks * 4 + lh;
            const int aoff = aoff0 + ((kb ^ (jrow & 7)) << 3);
            bf16x8 kh8 = *(const bf16x8*)&KshH[aoff];
            bf16x8 kl8 = *(const bf16x8*)&KshL[aoff];
#pragma unroll
            for (int fm = 0; fm < 2; ++fm) {
                sacc[fm] = __builtin_amdgcn_mfma_f32_16x16x32_bf16(kh8, qah[fm][ks], sacc[fm], 0, 0, 0);
                sacc[fm] = __builtin_amdgcn_mfma_f32_16x16x32_bf16(kh8, qal[fm][ks], sacc[fm], 0, 0, 0);
                sacc[fm] = __builtin_amdgcn_mfma_f32_16x16x32_bf16(kl8, qah[fm][ks], sacc[fm], 0, 0, 0);
            }
        }
        float4 y2v = *(const float4*)(kn2 + (bh << 11) + j0 + w * 16 + lh * 4);
        bf16x8 ebf[2];
#pragma unroll
        for (int fm = 0; fm < 2; ++fm) {
            const float x2 = x2s[fm];
            float es[4];
#pragma unroll
            for (int r = 0; r < 4; ++r) {
                float xy = sacc[fm][r];
                float y2 = ((const float*)&y2v)[r];
                float A_ = 1.f - 2.f * xy + y2;
                float Bc = 1.f - x2;
                float num2 = A_ * A_ * x2 + Bc * Bc * y2 - 2.f * A_ * Bc * xy;
                float den  = fmaxf(1.f - 2.f * xy + x2 * y2, 1e-15f);
                float sn   = __builtin_amdgcn_sqrtf(fmaxf(num2, 0.f));
                float dm   = den - sn;
                dm = fmaxf(dm, (den + sn) * 5e-8f);
                float rr = (den + sn) * __builtin_amdgcn_rcpf(dm);
                float e = __builtin_amdgcn_exp2f(-0.125f * __builtin_amdgcn_logf(rr));
                es[r] = e;
                rsp[fm] += e;
            }
            unsigned p0 = (unsigned)f2bf(es[0]) | ((unsigned)f2bf(es[1]) << 16);
            unsigned p1 = (unsigned)f2bf(es[2]) | ((unsigned)f2bf(es[3]) << 16);
            ebf[fm] = mk_bf8(p0, p1);
            const int prow = fm * 16 + lr;
            *(uint2*)&Psh[prow * 64 + ((pgj ^ (prow & 7)) << 3) + pjo] = make_uint2(p0, p1);
        }
#pragma unroll
        for (int g2 = 0; g2 < 4; ++g2) {
            const int dk = g2 * 16 + lr;
            uint2 lvp = *(const uint2*)&LVsh[dk * 64 + ((pgj ^ (dk & 7)) << 3) + pjo];
            bf16x8 bfr = mk_bf8(lvp.x, lvp.y);
            pvacc[0][g2] = __builtin_amdgcn_mfma_f32_16x16x32_bf16(ebf[0], bfr, pvacc[0][g2], 0, 0, 0);
            pvacc[1][g2] = __builtin_amdgcn_mfma_f32_16x16x32_bf16(ebf[1], bfr, pvacc[1][g2], 0, 0, 0);
        }
    }
    __syncthreads();
    {
        uint4 ev = *(const uint4*)&Psh[fl_row * 64 + ((fl_g ^ (fl_row & 7)) << 3)];
        *(uint4*)(eattn + ((size_t)(bh << 11) + i0 + fl_row) * 4096 + 31 * 64 + fl_g * 8) = ev;
    }
#pragma unroll
    for (int fm = 0; fm < 2; ++fm) {
        rsp[fm] += __shfl_xor(rsp[fm], 16, 64);
        rsp[fm] += __shfl_xor(rsp[fm], 32, 64);
    }
    __syncthreads();
    if (l < 16) { rsL[w][l] = rsp[0]; rsL[w][16 + l] = rsp[1]; }
#pragma unroll
    for (int fm = 0; fm < 2; ++fm)
#pragma unroll
        for (int g2 = 0; g2 < 4; ++g2)
#pragma unroll
            for (int r = 0; r < 4; ++r)
                Pmid[w * 2048 + (fm * 16 + lh * 4 + r) * 64 + g2 * 16 + lr] = pvacc[fm][g2][r];
    __syncthreads();
    if (tid < 32)
        invSL[tid] = 1.f / (rsL[0][tid] + rsL[1][tid] + rsL[2][tid] + rsL[3][tid]);
    __syncthreads();
    {
        const int q = tid >> 3;
        const int c8 = (tid & 7) * 8;
        float m[8];
#pragma unroll
        for (int i = 0; i < 8; i += 4) {
            float4 a0 = *(const float4*)&Pmid[0 * 2048 + q * 64 + c8 + i];
            float4 a1 = *(const float4*)&Pmid[1 * 2048 + q * 64 + c8 + i];
            float4 a2 = *(const float4*)&Pmid[2 * 2048 + q * 64 + c8 + i];
            float4 a3 = *(const float4*)&Pmid[3 * 2048 + q * 64 + c8 + i];
            m[i + 0] = (a0.x + a1.x) + (a2.x + a3.x);
            m[i + 1] = (a0.y + a1.y) + (a2.y + a3.y);
            m[i + 2] = (a0.z + a1.z) + (a2.z + a3.z);
            m[i + 3] = (a0.w + a1.w) + (a2.w + a3.w);
        }
        const float is = invSL[q];
        float ns = 0.f;
#pragma unroll
        for (int i = 0; i < 8; ++i) { m[i] *= is; ns = fmaf(m[i], m[i], ns); }
        ns += __shfl_xor(ns, 1, 64);
        ns += __shfl_xor(ns, 2, 64);
        ns += __shfl_xor(ns, 4, 64);
        float un = sqrtf(fmaxf(ns, 1e-15f));
        float coef = tanhf(un) / un;
        float* dst = outcat + (size_t)(b * kS + i0 + q) * kD + h * kDK + c8;
        *(float4*)dst       = make_float4(m[0] * coef, m[1] * coef, m[2] * coef, m[3] * coef);
        *(float4*)(dst + 4) = make_float4(m[4] * coef, m[5] * coef, m[6] * coef, m[7] * coef);
    }
    // ---- tail: in-place expansion, 2 rows per barrier ----
    for (int r = 0; r < 32; r += 2) {
        const size_t rb0 = (size_t)(bh << 11) + i0 + r;
        const size_t rb1 = rb0 + 1;
        uint4 ev0 = *(const uint4*)(eattn + rb0 * 4096 + tid * 8);
        uint4 ev1 = *(const uint4*)(eattn + rb1 * 4096 + tid * 8);
        const float is0 = invSL[r];
        const float is1 = invSL[r + 1];
        __syncthreads();
        float o[8];
        o[0] = __uint_as_float(ev0.x << 16) * is0;
        o[1] = __uint_as_float(ev0.x & 0xFFFF0000u) * is0;
        o[2] = __uint_as_float(ev0.y << 16) * is0;
        o[3] = __uint_as_float(ev0.y & 0xFFFF0000u) * is0;
        o[4] = __uint_as_float(ev0.z << 16) * is0;
        o[5] = __uint_as_float(ev0.z & 0xFFFF0000u) * is0;
        o[6] = __uint_as_float(ev0.w << 16) * is0;
        o[7] = __uint_as_float(ev0.w & 0xFFFF0000u) * is0;
        float* d0 = attn + rb0 * kS + tid * 8;
        *(float4*)d0       = make_float4(o[0], o[1], o[2], o[3]);
        *(float4*)(d0 + 4) = make_float4(o[4], o[5], o[6], o[7]);
        o[0] = __uint_as_float(ev1.x << 16) * is1;
        o[1] = __uint_as_float(ev1.x & 0xFFFF0000u) * is1;
        o[2] = __uint_as_float(ev1.y << 16) * is1;
        o[3] = __uint_as_float(ev1.y & 0xFFFF0000u) * is1;
        o[4] = __uint_as_float(ev1.z << 16) * is1;
        o[5] = __uint_as_float(ev1.z & 0xFFFF0000u) * is1;
        o[6] = __uint_as_float(ev1.w << 16) * is1;
        o[7] = __uint_as_float(ev1.w & 0xFFFF0000u) * is1;
        float* d1 = attn + rb1 * kS + tid * 8;
        *(float4*)d1       = make_float4(o[0], o[1], o[2], o[3]);
        *(float4*)(d1 + 4) = make_float4(o[4], o[5], o[6], o[7]);
    }
}

} // namespace

extern "C" void kernel_launch(void* const* d_in, const int* in_sizes, int n_in,
                              void* d_out, int out_size, void* d_ws, size_t ws_size,
                              hipStream_t stream) {
    const float* q  = (const float*)d_in[0];
    const float* k  = (const float*)d_in[1];
    const float* v  = (const float*)d_in[2];
    const float* Wq = (const float*)d_in[3];
    const float* bq = (const float*)d_in[4];
    const float* Wk = (const float*)d_in[5];
    const float* bk = (const float*)d_in[6];
    const float* Wv = (const float*)d_in[7];
    const float* bv = (const float*)d_in[8];
    const float* Wo = (const float*)d_in[9];
    const float* bo = (const float*)d_in[10];

    float* out  = (float*)d_out;
    float* attn = out + (size_t)kM * kD;   // out (2M floats), then attn (64M floats)

    constexpr size_t NBUF = (size_t)kM * kD; // 2,097,152 floats (8 MB)
    float* ws  = (float*)d_ws;
    float* A0  = ws;              // Qp
    float* A1  = ws + NBUF;       // Kp -> later outcat
    float* A2  = ws + 2 * NBUF;   // Qhi/Qlo bf16 -> mx for final gemm
    float* A3  = ws + 3 * NBUF;   // mxq -> later LVbT (4MB)
    float* qn2 = ws + 4 * NBUF;                       // 32768 floats
    float* kn2 = qn2 + (size_t)kBH * kS;              // 32768 floats

    // projection scratch in the (later fully overwritten) attn region:
    float* mxq  = A3;
    float* mxk  = attn;                // attn rows 0..1023
    float* mxv  = attn + NBUF;         // attn rows 1024..2047
    float* VpBuf = attn + 2 * NBUF;    // attn rows 2048..3071

    constexpr size_t HP = (size_t)kBH * kS * kDK;   // 2,097,152 ushorts = 4 MB per plane
    unsigned short* Qhi = (unsigned short*)A2;
    unsigned short* Qlo = Qhi + HP;
    unsigned short* Khi = (unsigned short*)out;     // out region free until final rowops
    unsigned short* Klo = Khi + HP;
    unsigned short* LVbT = (unsigned short*)A3;     // overwrites mxq (dead after rowops3)

    dim3 gg(kM / 64, kD / 64);
    dim3 gg3(kM / 64, kD / 64, 3);
    dim3 rr3(kM, 3);

    gemm_mfma3<<<gg3, 256, 0, stream>>>(q, k, v, Wq, Wk, Wv, mxq, mxk, mxv);
    rowops3<<<rr3, 256, 0, stream>>>(q, k, v, mxq, mxk, mxv, bq, bk, bv, A0, A1, VpBuf);

    prep3<<<kBH * 32, 256, 0, stream>>>(A0, A1, VpBuf, qn2, kn2, LVbT,
                                        Qhi, Qlo, Khi, Klo);

    fused_attn<<<kBH * (kS / 32), 256, 0, stream>>>(Qhi, Qlo, Khi, Klo, LVbT,
                                                    qn2, kn2, attn, A1);

    gemm_mfma<<<gg, 256, 0, stream>>>(A1, Wo, A2);
    rowops<<<kM, 256, 0, stream>>>(A1, A2, bo, out);
}